// Round 5
// baseline (475.283 us; speedup 1.0000x reference)
//
#include <hip/hip_runtime.h>
#include <hip/hip_bf16.h>
#include <stdint.h>

#define B_DIM 4
#define NKK 4096
#define NQQ 4096
#define DD 64
#define HH 256

typedef __attribute__((ext_vector_type(4))) float floatx4;
typedef __attribute__((ext_vector_type(2))) float floatx2;
typedef __attribute__((ext_vector_type(8))) short bf16x8;

__device__ __forceinline__ float fexp2(float x) { return __builtin_amdgcn_exp2f(x); }
__device__ __forceinline__ unsigned fbits(float x) { return __float_as_uint(x); }
__device__ __forceinline__ float bf2f(unsigned short u) { return __uint_as_float(((unsigned)u) << 16); }

// a - b on both packed halves in ONE VOP3P instruction.
__device__ __forceinline__ floatx2 pk_sub(floatx2 a, floatx2 b) {
  floatx2 d;
  asm("v_pk_add_f32 %0, %1, %2 neg_lo:[0,1] neg_hi:[0,1]" : "=v"(d) : "v"(a), "v"(b));
  return d;
}

// round-to-nearest-even split: x = h + l, h/l bf16, rel err ~2^-17
__device__ __forceinline__ void splitbf(float x, unsigned short& h, unsigned short& l) {
  unsigned u = fbits(x);
  unsigned hu = (u + 0x7fff + ((u >> 16) & 1)) & 0xffff0000u;
  h = (unsigned short)(hu >> 16);
  l = (unsigned short)(fbits(x - __uint_as_float(hu)) >> 16);
}

// psB row stride in shorts: 36 -> 72 B = 18 dwords; 18r mod 32 distinct for all
// 16 simultaneously-read rows -> conflict-free A-frag b128 reads (r0-verified).
#define PSTRIDE 36

// ---------------------------------------------------------------------------
// Weight split prep.
// ---------------------------------------------------------------------------
__global__ __launch_bounds__(256) void wsplit_kernel(
    const float* __restrict__ W1a, const float* __restrict__ W2a, const float* __restrict__ W3a,
    const float* __restrict__ W1b, const float* __restrict__ W2b, const float* __restrict__ W3b,
    unsigned short* __restrict__ sp)
{
  int idx = blockIdx.x * 256 + threadIdx.x;       // 0..196607
  const int set = idx >= 98304;
  int r = idx - set * 98304;
  unsigned short* base = sp + (size_t)set * 196608;
  const float* src;
  unsigned short *dh, *dl;
  int j;
  if (r < 16384)      { src = set ? W1b : W1a; dh = base;          dl = base + 16384;  j = r; }
  else if (r < 81920) { src = set ? W2b : W2a; dh = base + 32768;  dl = base + 98304;  j = r - 16384; }
  else                { src = set ? W3b : W3a; dh = base + 163840; dl = base + 180224; j = r - 81920; }
  unsigned short h, l;
  splitbf(src[j], h, l);
  dh[j] = h; dl[j] = l;
}

// ---------------------------------------------------------------------------
// V pre-transpose: Vt[b][d][k] = bf16(V[b][k][d]).
// ---------------------------------------------------------------------------
__global__ __launch_bounds__(256) void vtrans_kernel(
    const float* __restrict__ V, unsigned short* __restrict__ Vt)
{
  __shared__ unsigned short t[64][80];
  const int tid = threadIdx.x;
  const int b = blockIdx.y;
  const int k0 = blockIdx.x * 64;
  const float4* V4 = (const float4*)V;
  {
    const int r = tid & 63;
    const int c4 = tid >> 6;
#pragma unroll
    for (int j = 0; j < 4; ++j) {
      float4 f = V4[((size_t)(b * NKK + k0 + r)) * 16 + c4 * 4 + j];
      const int d0 = c4 * 16 + j * 4;
      t[d0 + 0][r] = (unsigned short)(fbits(f.x) >> 16);
      t[d0 + 1][r] = (unsigned short)(fbits(f.y) >> 16);
      t[d0 + 2][r] = (unsigned short)(fbits(f.z) >> 16);
      t[d0 + 3][r] = (unsigned short)(fbits(f.w) >> 16);
    }
  }
  __syncthreads();
  {
    const int d = tid >> 2;
    const int kc = tid & 3;
    uint4 u0 = *(const uint4*)&t[d][kc * 16];
    uint4 u1 = *(const uint4*)&t[d][kc * 16 + 8];
    unsigned short* dst = Vt + ((size_t)(b * 64 + d)) * NKK + k0 + kc * 16;
    *(uint4*)dst = u0;
    *(uint4*)(dst + 8) = u1;
  }
}

// ---------------------------------------------------------------------------
// MLP on MFMA, split-bf16 (hh+lh+hl). 64 tokens/WG, 512 threads (8 waves).
// ---------------------------------------------------------------------------
#define HSTRIDE 264   // shorts; 528B = 132 dwords = 4 mod 32 -> 2-way (free)
__global__ __launch_bounds__(512, 1) void mlpmm_kernel(
    const float* __restrict__ KEY, const float* __restrict__ QUERY,
    const float* __restrict__ B1a, const float* __restrict__ B2a, const float* __restrict__ B3a,
    const float* __restrict__ B1b, const float* __restrict__ B2b, const float* __restrict__ B3b,
    const unsigned short* __restrict__ sp,
    float* __restrict__ Ks, float* __restrict__ Qs, float* __restrict__ Wo)
{
  __shared__ unsigned short Xh[64][72], Xl[64][72];             // 18 KB
  __shared__ unsigned short Hsh[64][HSTRIDE], Hsl[64][HSTRIDE]; // 66 KB
  const int tid = threadIdx.x;
  const int w = tid >> 6;        // 0..7
  const int lane = tid & 63;
  const int l15 = lane & 15;
  const int quad = lane >> 4;

  const int g = blockIdx.x;
  const float* X;
  float* outp;
  int mulx, t0;
  const unsigned short* wb;
  const float *b1, *b2, *b3;
  if (g < 256)      { X = KEY;   outp = Ks; mulx = 1; t0 = g * 64;         wb = sp;          b1 = B1a; b2 = B2a; b3 = B3a; }
  else if (g < 512) { X = QUERY; outp = Qs; mulx = 1; t0 = (g - 256) * 64; wb = sp;          b1 = B1a; b2 = B2a; b3 = B3a; }
  else              { X = QUERY; outp = Wo; mulx = 0; t0 = (g - 512) * 64; wb = sp + 196608; b1 = B1b; b2 = B2b; b3 = B3b; }
  const unsigned short* W1h = wb;
  const unsigned short* W1l = wb + 16384;
  const unsigned short* W2h = wb + 32768;
  const unsigned short* W2l = wb + 98304;
  const unsigned short* W3h = wb + 163840;
  const unsigned short* W3l = wb + 180224;

  // ---- stage X tile (64 rows), split to bf16 h/l ----
  {
    const int t = tid >> 3;
    const int c = (tid & 7) * 8;
    float4 a = *(const float4*)&X[(size_t)(t0 + t) * 64 + c];
    float4 b = *(const float4*)&X[(size_t)(t0 + t) * 64 + c + 4];
    float v[8] = {a.x, a.y, a.z, a.w, b.x, b.y, b.z, b.w};
    unsigned short hs[8], ls[8];
#pragma unroll
    for (int e = 0; e < 8; ++e) splitbf(v[e], hs[e], ls[e]);
    uint4 uh = make_uint4(hs[0] | ((unsigned)hs[1] << 16), hs[2] | ((unsigned)hs[3] << 16),
                          hs[4] | ((unsigned)hs[5] << 16), hs[6] | ((unsigned)hs[7] << 16));
    uint4 ul = make_uint4(ls[0] | ((unsigned)ls[1] << 16), ls[2] | ((unsigned)ls[3] << 16),
                          ls[4] | ((unsigned)ls[5] << 16), ls[6] | ((unsigned)ls[7] << 16));
    *(uint4*)&Xh[t][c] = uh;
    *(uint4*)&Xl[t][c] = ul;
  }
  __syncthreads();

  // ---- layer 1: [64x64] x [64->256] ----
  {
    floatx4 acc[4][2];
#pragma unroll
    for (int nb = 0; nb < 2; ++nb) {
      const float bias = b1[(w * 2 + nb) * 16 + l15];
#pragma unroll
      for (int mb = 0; mb < 4; ++mb) acc[mb][nb] = (floatx4){bias, bias, bias, bias};
    }
#pragma unroll
    for (int kb = 0; kb < 2; ++kb) {
      bf16x8 Ah[4], Al[4];
#pragma unroll
      for (int mb = 0; mb < 4; ++mb) {
        Ah[mb] = *(const bf16x8*)&Xh[mb * 16 + l15][kb * 32 + quad * 8];
        Al[mb] = *(const bf16x8*)&Xl[mb * 16 + l15][kb * 32 + quad * 8];
      }
#pragma unroll
      for (int nb = 0; nb < 2; ++nb) {
        const int n0 = (w * 2 + nb) * 16;
        bf16x8 Bh = *(const bf16x8*)&W1h[(size_t)(n0 + l15) * 64 + kb * 32 + quad * 8];
        bf16x8 Bl = *(const bf16x8*)&W1l[(size_t)(n0 + l15) * 64 + kb * 32 + quad * 8];
#pragma unroll
        for (int mb = 0; mb < 4; ++mb) {
          acc[mb][nb] = __builtin_amdgcn_mfma_f32_16x16x32_bf16(Ah[mb], Bh, acc[mb][nb], 0, 0, 0);
          acc[mb][nb] = __builtin_amdgcn_mfma_f32_16x16x32_bf16(Al[mb], Bh, acc[mb][nb], 0, 0, 0);
          acc[mb][nb] = __builtin_amdgcn_mfma_f32_16x16x32_bf16(Ah[mb], Bl, acc[mb][nb], 0, 0, 0);
        }
      }
    }
#pragma unroll
    for (int mb = 0; mb < 4; ++mb)
#pragma unroll
      for (int nb = 0; nb < 2; ++nb) {
        const int col = (w * 2 + nb) * 16 + l15;
#pragma unroll
        for (int r = 0; r < 4; ++r) {
          const int row = mb * 16 + quad * 4 + r;
          float v = fmaxf(acc[mb][nb][r], 0.0f);
          unsigned short h, l;
          splitbf(v, h, l);
          Hsh[row][col] = h;
          Hsl[row][col] = l;
        }
      }
  }
  __syncthreads();

  // ---- layer 2: [64x256] x [256->256] ----
  {
    floatx4 acc2[4][2];
#pragma unroll
    for (int nb = 0; nb < 2; ++nb) {
      const float bias = b2[(w * 2 + nb) * 16 + l15];
#pragma unroll
      for (int mb = 0; mb < 4; ++mb) acc2[mb][nb] = (floatx4){bias, bias, bias, bias};
    }
#pragma unroll
    for (int kb = 0; kb < 8; ++kb) {
      bf16x8 Ah[4], Al[4];
#pragma unroll
      for (int mb = 0; mb < 4; ++mb) {
        Ah[mb] = *(const bf16x8*)&Hsh[mb * 16 + l15][kb * 32 + quad * 8];
        Al[mb] = *(const bf16x8*)&Hsl[mb * 16 + l15][kb * 32 + quad * 8];
      }
#pragma unroll
      for (int nb = 0; nb < 2; ++nb) {
        const int n0 = (w * 2 + nb) * 16;
        bf16x8 Bh = *(const bf16x8*)&W2h[(size_t)(n0 + l15) * 256 + kb * 32 + quad * 8];
        bf16x8 Bl = *(const bf16x8*)&W2l[(size_t)(n0 + l15) * 256 + kb * 32 + quad * 8];
#pragma unroll
        for (int mb = 0; mb < 4; ++mb) {
          acc2[mb][nb] = __builtin_amdgcn_mfma_f32_16x16x32_bf16(Ah[mb], Bh, acc2[mb][nb], 0, 0, 0);
          acc2[mb][nb] = __builtin_amdgcn_mfma_f32_16x16x32_bf16(Al[mb], Bh, acc2[mb][nb], 0, 0, 0);
          acc2[mb][nb] = __builtin_amdgcn_mfma_f32_16x16x32_bf16(Ah[mb], Bl, acc2[mb][nb], 0, 0, 0);
        }
      }
    }
    __syncthreads();
#pragma unroll
    for (int mb = 0; mb < 4; ++mb)
#pragma unroll
      for (int nb = 0; nb < 2; ++nb) {
        const int col = (w * 2 + nb) * 16 + l15;
#pragma unroll
        for (int r = 0; r < 4; ++r) {
          const int row = mb * 16 + quad * 4 + r;
          float v = fmaxf(acc2[mb][nb][r], 0.0f);
          unsigned short h, l;
          splitbf(v, h, l);
          Hsh[row][col] = h;
          Hsl[row][col] = l;
        }
      }
  }
  __syncthreads();

  // ---- layer 3: [64x256] x [256->64] ----
  {
    const int mp = (w >> 2) * 2;
    const int n0 = (w & 3) * 16;
    const float bias = b3[n0 + l15];
    floatx4 acc3[2];
#pragma unroll
    for (int m = 0; m < 2; ++m) acc3[m] = (floatx4){bias, bias, bias, bias};
#pragma unroll
    for (int kb = 0; kb < 8; ++kb) {
      bf16x8 Ah[2], Al[2];
#pragma unroll
      for (int m = 0; m < 2; ++m) {
        Ah[m] = *(const bf16x8*)&Hsh[(mp + m) * 16 + l15][kb * 32 + quad * 8];
        Al[m] = *(const bf16x8*)&Hsl[(mp + m) * 16 + l15][kb * 32 + quad * 8];
      }
      bf16x8 Bh = *(const bf16x8*)&W3h[(size_t)(n0 + l15) * 256 + kb * 32 + quad * 8];
      bf16x8 Bl = *(const bf16x8*)&W3l[(size_t)(n0 + l15) * 256 + kb * 32 + quad * 8];
#pragma unroll
      for (int m = 0; m < 2; ++m) {
        acc3[m] = __builtin_amdgcn_mfma_f32_16x16x32_bf16(Ah[m], Bh, acc3[m], 0, 0, 0);
        acc3[m] = __builtin_amdgcn_mfma_f32_16x16x32_bf16(Al[m], Bh, acc3[m], 0, 0, 0);
        acc3[m] = __builtin_amdgcn_mfma_f32_16x16x32_bf16(Ah[m], Bl, acc3[m], 0, 0, 0);
      }
    }
#pragma unroll
    for (int m = 0; m < 2; ++m)
#pragma unroll
      for (int r = 0; r < 4; ++r) {
        const int row = (mp + m) * 16 + quad * 4 + r;
        const int col = n0 + l15;
        float v = acc3[m][r];
        if (mulx) v *= (bf2f(Xh[row][col]) + bf2f(Xl[row][col]));
        outp[(size_t)(t0 + row) * 64 + col] = v;
      }
  }
}

// ---------------------------------------------------------------------------
// Flash attention, round-13: 64q x 32k wave tile with SHARED K-slice.
// r4 taught: wave-private slices (4 slices/block) quadruple the per-combo
// L2 footprint -> 12 resident combos x 4.6 MB-class working set -> thrash
// (FETCH 346 MB). Fix: all 4 waves process the SAME slice bz, taking
// interleaved 32-key tiles (wave w gets tiles 4*it+w). The in-block 4-wave
// merge (verified in r4) combines arbitrary k-partitions. Per-combo unique
// K+Vt = (4096/Z)*384 B; at Z=8 = 196 KB -> 12 resident combos = 2.4 MB +
// 0.5 MB Q < 4 MB L2 with margin (r0 fit at exactly 4.0).
// Z=8: 512-key slices = 16 tiles = 4 even iters/wave; grid (64,4,8)=2048.
// DS: 192 b128 reads per 2048 pairs = 0.375/pair (-25% vs r0).
// LDS 48 KB -> 3 blocks/CU (r0's proven occupancy geometry).
// Tiers: Z=8 needs 50.1 MB ws; Z=4 needs 32,768,000 B (PROVEN available --
// r1's partial path ran at exactly this size); Z=1 last resort.
// ---------------------------------------------------------------------------
template <int Z>
__global__ __launch_bounds__(256, 3) void attn_kernel(
    const float* __restrict__ Ksg, const float* __restrict__ Qsg,
    const unsigned short* __restrict__ Vtg, const float* __restrict__ Wog,
    float* __restrict__ outp,
    float* __restrict__ Pm, float* __restrict__ Pl, float* __restrict__ PO)
{
  // 49152 B exactly:
  //   lds[0    .. 4096)  qsA [64][64] f32, slot-XOR swizzled (16 KB)
  //                       epilogue overlay: m/l per (wave,row) (512 f32)
  //   lds[4096 + w*2048) ksw per-wave [32][64] f32 swizzled K tile (8 KB)
  //                       overlays: psB @ +0 (4608 B), abA @ +4608 (256 B),
  //                       epilogue O half-tile [32][64] f32.
  __shared__ float lds[12288];
  float* qsA = lds;

  const int tid  = threadIdx.x;
  const int w    = tid >> 6;
  const int lane = tid & 63;
  const int lq   = lane >> 3;
  const int lk   = lane & 7;
  const int l15  = lane & 15;
  const int quad = lane >> 4;
  const int b    = blockIdx.y;
  const int bx   = blockIdx.x;
  const int bz   = blockIdx.z;
  const int qt   = bx * 64;

  float* ksw = lds + 4096 + w * 2048;

  // ---- stage Q tile (64 rows, slot-XOR swizzled) ----
  {
    const int row = tid >> 2;          // 0..63
    const int c4  = (tid & 3) * 4;     // 16B-slot base
    const int r7  = row & 7;
    const float4* Q4 = (const float4*)Qsg;
#pragma unroll
    for (int jj = 0; jj < 4; ++jj) {
      float4 g = Q4[(size_t)(b * NQQ + qt + row) * 16 + c4 + jj];
      *(float4*)&qsA[row * 64 + (((c4 + jj) ^ r7) << 2)] = g;
    }
  }
  __syncthreads();

  float m_i[8], l_i[8];
  floatx4 acc[4][4];
#pragma unroll
  for (int i = 0; i < 8; ++i) { m_i[i] = -3.0e38f; l_i[i] = 0.0f; }
#pragma unroll
  for (int mb = 0; mb < 4; ++mb)
#pragma unroll
    for (int nb = 0; nb < 4; ++nb)
#pragma unroll
      for (int r = 0; r < 4; ++r) acc[mb][nb][r] = 0.0f;

  // shared slice: all 4 waves cover slice bz; wave w takes tiles 4*it + w
  constexpr int ITERS = 32 / Z;                  // per-wave 32-key tiles
  const int kstart = bz * (NKK / Z) + w * 32;    // wave's first tile
  // per-iter k advance = 4 tiles = 128 keys

  const float4* K4 = (const float4*)Ksg;
  const float NEG_HALF_LOG2E = -0.72134752044448170f;  // -0.5*log2(e)

  const int krow = lane >> 4;
  const int kci  = lane & 15;

  const unsigned short* vg0 = Vtg + ((size_t)b * 64 + l15) * NKK + kstart + quad * 8;

  float4 kpre[8];
  uint4 vtpre[4];
#pragma unroll
  for (int c = 0; c < 8; ++c)
    kpre[c] = K4[(size_t)(b * NKK + kstart + c * 4 + krow) * 16 + kci];
#pragma unroll
  for (int nb = 0; nb < 4; ++nb)
    vtpre[nb] = *(const uint4*)(vg0 + (size_t)nb * 16 * NKK);

  const char* qbase = (const char*)qsA + (lq << 8);
  const char* kbase = (const char*)ksw + (lk << 8);
  const int lq16 = lq << 4, lk16 = lk << 4;
  unsigned short* psw = (unsigned short*)ksw;            // overlay on dead K
  float* abw = (float*)((char*)ksw + 4608);              // overlay on dead K

  for (int it = 0; it < ITERS; ++it) {
    // ---- store prefetched K tile -> LDS (wave-private, slot-XOR) ----
#pragma unroll
    for (int c = 0; c < 8; ++c) {
      const int row  = c * 4 + krow;
      const int slot = kci ^ (row & 7);
      *(float4*)((char*)ksw + row * 256 + (slot << 4)) = kpre[c];
    }

    // ---- prefetch next K tile (wave stride = 128 keys) ----
    {
      const int kn = kstart + ((it + 1 < ITERS) ? (it + 1) : it) * 128;
#pragma unroll
      for (int c = 0; c < 8; ++c)
        kpre[c] = K4[(size_t)(b * NKK + kn + c * 4 + krow) * 16 + kci];
    }

    // ---- score: s[i][j] = sum_d |K[lk+8j] - Q[lq+8i]| over 64 dims ----
    float s[8][4];
#pragma unroll
    for (int i = 0; i < 8; ++i)
#pragma unroll
      for (int j = 0; j < 4; ++j) s[i][j] = 0.0f;

#pragma unroll
    for (int dc = 0; dc < 16; ++dc) {
      const floatx4* qp = (const floatx4*)(qbase + ((dc << 4) ^ lq16));
      const floatx4* kp = (const floatx4*)(kbase + ((dc << 4) ^ lk16));
      floatx4 kv[4];
#pragma unroll
      for (int j = 0; j < 4; ++j) kv[j] = kp[j * 128];
#pragma unroll
      for (int i = 0; i < 8; ++i) {
        const floatx4 qv = qp[i * 128];
        const floatx2 qlo = qv.lo, qhi = qv.hi;
#pragma unroll
        for (int j = 0; j < 4; ++j) {
          floatx2 d0 = pk_sub(qlo, kv[j].lo);
          floatx2 d1 = pk_sub(qhi, kv[j].hi);
          s[i][j] += __builtin_fabsf(d0.x);
          s[i][j] += __builtin_fabsf(d0.y);
          s[i][j] += __builtin_fabsf(d1.x);
          s[i][j] += __builtin_fabsf(d1.y);
        }
      }
    }

    // ---- online softmax (base-2); row max via min(s) ----
    float a_row[8];
#pragma unroll
    for (int i = 0; i < 8; ++i) {
      float smin = fminf(fminf(s[i][0], s[i][1]), fminf(s[i][2], s[i][3]));
      smin = fminf(smin, __shfl_xor(smin, 1));
      smin = fminf(smin, __shfl_xor(smin, 2));
      smin = fminf(smin, __shfl_xor(smin, 4));
      const float tmax = smin * smin * NEG_HALF_LOG2E;
      const float mn = fmaxf(m_i[i], tmax);
      a_row[i] = fexp2(m_i[i] - mn);
      m_i[i] = mn;
      float ps = 0.0f;
#pragma unroll
      for (int j = 0; j < 4; ++j) {
        const float sv = s[i][j];
        const float e = fexp2(fmaf(sv * NEG_HALF_LOG2E, sv, -mn));
        ps += e;
        psw[(lq + 8 * i) * PSTRIDE + lk + 8 * j] = (unsigned short)(fbits(e) >> 16);
      }
      l_i[i] = fmaf(l_i[i], a_row[i], ps);
    }
    if (lk == 0) {
#pragma unroll
      for (int i = 0; i < 8; ++i) abw[lq + 8 * i] = a_row[i];
    }

    // ---- P.V on MFMA (V B-frags from prefetched registers) ----
    {
      bf16x8 afrag[4];
#pragma unroll
      for (int mb = 0; mb < 4; ++mb)
        afrag[mb] = *(const bf16x8*)&psw[(mb * 16 + l15) * PSTRIDE + quad * 8];
      floatx4 arv[4];
#pragma unroll
      for (int mb = 0; mb < 4; ++mb)
        arv[mb] = *(const floatx4*)&abw[mb * 16 + quad * 4];

#pragma unroll
      for (int nb = 0; nb < 4; ++nb) {
        bf16x8 bfrag = __builtin_bit_cast(bf16x8, vtpre[nb]);
#pragma unroll
        for (int mb = 0; mb < 4; ++mb) {
          acc[mb][nb] *= arv[mb];
          acc[mb][nb] = __builtin_amdgcn_mfma_f32_16x16x32_bf16(afrag[mb], bfrag, acc[mb][nb], 0, 0, 0);
        }
      }
    }

    // ---- prefetch next V tile (wave stride = 128 keys) ----
    {
      const int koff = ((it + 1 < ITERS) ? (it + 1) : it) * 128;
#pragma unroll
      for (int nb = 0; nb < 4; ++nb)
        vtpre[nb] = *(const uint4*)(vg0 + (size_t)nb * 16 * NKK + koff);
    }
  }

  // ---- epilogue: reduce l over lk; publish m,l into qsA (dead after loop);
  //      2-pass in-block merge of O halves through wave K regions ----
#pragma unroll
  for (int i = 0; i < 8; ++i) {
    float l = l_i[i];
    l += __shfl_xor(l, 1);
    l += __shfl_xor(l, 2);
    l += __shfl_xor(l, 4);
    l_i[i] = l;
  }
  __syncthreads();                    // all waves done with qsA / their ksw
  if (lk == 0) {
#pragma unroll
    for (int i = 0; i < 8; ++i) {
      const int row = lq + 8 * i;
      qsA[w * 128 + row]      = m_i[i];
      qsA[w * 128 + 64 + row] = l_i[i];
    }
  }

#pragma unroll
  for (int half = 0; half < 2; ++half) {
    // store this half's O rows (32) into the wave's K region
#pragma unroll
    for (int mb2 = 0; mb2 < 2; ++mb2)
#pragma unroll
      for (int nb = 0; nb < 4; ++nb)
#pragma unroll
        for (int r = 0; r < 4; ++r)
          ksw[(mb2 * 16 + quad * 4 + r) * 64 + nb * 16 + l15] = acc[half * 2 + mb2][nb][r];
    __syncthreads();
    {
      const int q = tid >> 3;              // 0..31
      const int dbase = (tid & 7) * 8;
      const int qrow = half * 32 + q;
      float mw[4], lw[4];
#pragma unroll
      for (int w2 = 0; w2 < 4; ++w2) {
        mw[w2] = qsA[w2 * 128 + qrow];
        lw[w2] = qsA[w2 * 128 + 64 + qrow];
      }
      const float M = fmaxf(fmaxf(mw[0], mw[1]), fmaxf(mw[2], mw[3]));
      const float s0 = fexp2(mw[0] - M), s1 = fexp2(mw[1] - M);
      const float s2v = fexp2(mw[2] - M), s3 = fexp2(mw[3] - M);
      const float L = lw[0] * s0 + lw[1] * s1 + lw[2] * s2v + lw[3] * s3;
      const float* ob = lds + 4096 + q * 64 + dbase;   // wave stride 2048 f32
      if (Z > 1) {
        const size_t p = (size_t)((bz * 4 + b) * 64 + bx);
        if (dbase == 0) { Pm[p * 64 + qrow] = M; Pl[p * 64 + qrow] = L; }
        float* dst = PO + p * 4096 + (size_t)qrow * 64 + dbase;
#pragma unroll
        for (int c = 0; c < 8; ++c)
          dst[c] = s0 * ob[c] + s1 * ob[2048 + c] + s2v * ob[4096 + c] + s3 * ob[6144 + c];
      } else {
        const float rL = 1.0f / L;
        const size_t gbase = (size_t)(b * NQQ + qt + qrow) * 64 + dbase;
#pragma unroll
        for (int c = 0; c < 8; ++c) {
          float o = s0 * ob[c] + s1 * ob[2048 + c] + s2v * ob[4096 + c] + s3 * ob[6144 + c];
          outp[gbase + c] = o * rL * Wog[gbase + c];
        }
      }
    }
    __syncthreads();
  }
}

// ---------------------------------------------------------------------------
// Merge the Z key-split partials: out = sum_z(w_z O_z)/L * Wo.
// ---------------------------------------------------------------------------
template <int NS>
__global__ __launch_bounds__(256) void amerge_kernel(
    const float* __restrict__ Pm, const float* __restrict__ Pl,
    const float* __restrict__ PO, const float* __restrict__ Wog,
    float* __restrict__ outp)
{
  const int tid = threadIdx.x;
  const int qtb = blockIdx.x;          // 0..63
  const int b = blockIdx.y;
  const int q = tid >> 2;              // 0..63
  const int dbase = (tid & 3) * 16;
  size_t p[NS];
  float mv[NS], lv[NS];
#pragma unroll
  for (int s = 0; s < NS; ++s) {
    p[s] = (size_t)((s * 4 + b) * 64 + qtb);
    mv[s] = Pm[p[s] * 64 + q];
    lv[s] = Pl[p[s] * 64 + q];
  }
  float M = mv[0];
#pragma unroll
  for (int s = 1; s < NS; ++s) M = fmaxf(M, mv[s]);
  float wsum = 0.0f, wgt[NS];
#pragma unroll
  for (int s = 0; s < NS; ++s) { wgt[s] = fexp2(mv[s] - M); wsum += wgt[s] * lv[s]; }
  const float rL = 1.0f / wsum;
  const size_t g = ((size_t)b * NQQ + qtb * 64 + q) * 64 + dbase;
#pragma unroll
  for (int c4 = 0; c4 < 4; ++c4) {
    float4 o = make_float4(0.f, 0.f, 0.f, 0.f);
#pragma unroll
    for (int s = 0; s < NS; ++s) {
      const float4 v = *(const float4*)&PO[p[s] * 4096 + (size_t)q * 64 + dbase + c4 * 4];
      o.x += wgt[s] * v.x; o.y += wgt[s] * v.y; o.z += wgt[s] * v.z; o.w += wgt[s] * v.w;
    }
    const float4 wv = *(const float4*)&Wog[g + c4 * 4];
    float4 r;
    r.x = o.x * rL * wv.x; r.y = o.y * rL * wv.y;
    r.z = o.z * rL * wv.z; r.w = o.w * rL * wv.w;
    *(float4*)&outp[g + c4 * 4] = r;
  }
}

// ---------------------------------------------------------------------------
extern "C" void kernel_launch(void* const* d_in, const int* in_sizes, int n_in,
                              void* d_out, int out_size, void* d_ws, size_t ws_size,
                              hipStream_t stream) {
  (void)in_sizes; (void)n_in; (void)out_size;
  const float* KEY   = (const float*)d_in[0];
  const float* VALUE = (const float*)d_in[1];
  const float* QUERY = (const float*)d_in[2];
  const float* W1w = (const float*)d_in[3];
  const float* W1b = (const float*)d_in[4];
  const float* W2w = (const float*)d_in[5];
  const float* W2b = (const float*)d_in[6];
  const float* W3w = (const float*)d_in[7];
  const float* W3b = (const float*)d_in[8];
  const float* Wo1w = (const float*)d_in[9];
  const float* Wo1b = (const float*)d_in[10];
  const float* Wo2w = (const float*)d_in[11];
  const float* Wo2b = (const float*)d_in[12];
  const float* Wo3w = (const float*)d_in[13];
  const float* Wo3b = (const float*)d_in[14];

  float* ws = (float*)d_ws;
  const size_t tsz = (size_t)B_DIM * NKK * DD;  // 1,048,576 floats
  float* Ks = ws;
  float* Qs = ws + tsz;
  float* Wo = ws + 2 * tsz;
  unsigned short* Vtg = (unsigned short*)(ws + 3 * tsz);  // tsz ushorts (2 MB)
  unsigned short* sp  = Vtg + tsz;                        // 2x196608 ushorts
  const size_t fbase0 = 3 * tsz + tsz / 2 + 196608;       // floats (3,866,624)
  float* Pm = ws + fbase0;
  float* outf = (float*)d_out;

  // per-tier float counts: Pm/Pl = Z*16384 each, PO = Z*1048576
  const size_t needZ8 = (fbase0 + 8ull * (2 * 16384 + 1048576)) * 4;  // 50,069,504 B
  const size_t needZ4 = (fbase0 + 4ull * (2 * 16384 + 1048576)) * 4;  // 32,768,000 B (r1-proven)

  wsplit_kernel<<<dim3(768), 256, 0, stream>>>(W1w, W2w, W3w, Wo1w, Wo2w, Wo3w, sp);
  vtrans_kernel<<<dim3(NKK / 64, B_DIM), 256, 0, stream>>>(VALUE, Vtg);
  mlpmm_kernel<<<dim3(768), 512, 0, stream>>>(
      KEY, QUERY, W1b, W2b, W3b, Wo1b, Wo2b, Wo3b, sp, Ks, Qs, Wo);
  if (ws_size >= needZ8) {
    float* Pl = Pm + 8 * 16384;
    float* PO = Pl + 8 * 16384;
    attn_kernel<8><<<dim3(64, B_DIM, 8), 256, 0, stream>>>(
        Ks, Qs, Vtg, Wo, outf, Pm, Pl, PO);
    amerge_kernel<8><<<dim3(64, B_DIM), 256, 0, stream>>>(Pm, Pl, PO, Wo, outf);
  } else if (ws_size >= needZ4) {
    float* Pl = Pm + 4 * 16384;
    float* PO = Pl + 4 * 16384;
    attn_kernel<4><<<dim3(64, B_DIM, 4), 256, 0, stream>>>(
        Ks, Qs, Vtg, Wo, outf, Pm, Pl, PO);
    amerge_kernel<4><<<dim3(64, B_DIM), 256, 0, stream>>>(Pm, Pl, PO, Wo, outf);
  } else {
    attn_kernel<1><<<dim3(64, B_DIM, 1), 256, 0, stream>>>(
        Ks, Qs, Vtg, Wo, outf, Pm, Pm, Pm);
  }
}

// Round 7
// 447.546 us; speedup vs baseline: 1.0620x; 1.0620x over previous
//
#include <hip/hip_runtime.h>
#include <hip/hip_bf16.h>
#include <stdint.h>

#define B_DIM 4
#define NKK 4096
#define NQQ 4096
#define DD 64
#define HH 256

typedef __attribute__((ext_vector_type(4))) float floatx4;
typedef __attribute__((ext_vector_type(2))) float floatx2;
typedef __attribute__((ext_vector_type(8))) short bf16x8;

__device__ __forceinline__ float fexp2(float x) { return __builtin_amdgcn_exp2f(x); }
__device__ __forceinline__ unsigned fbits(float x) { return __float_as_uint(x); }
__device__ __forceinline__ float bf2f(unsigned short u) { return __uint_as_float(((unsigned)u) << 16); }

// a - b on both packed halves in ONE VOP3P instruction (gfx950 has
// v_pk_add_f32 but no packed f32 max/abs -- abs lives on the consumer's
// input modifier).
__device__ __forceinline__ floatx2 pk_sub(floatx2 a, floatx2 b) {
  floatx2 d;
  asm("v_pk_add_f32 %0, %1, %2 neg_lo:[0,1] neg_hi:[0,1]" : "=v"(d) : "v"(a), "v"(b));
  return d;
}

// round-to-nearest-even split: x = h + l, h/l bf16, rel err ~2^-17
__device__ __forceinline__ void splitbf(float x, unsigned short& h, unsigned short& l) {
  unsigned u = fbits(x);
  unsigned hu = (u + 0x7fff + ((u >> 16) & 1)) & 0xffff0000u;
  h = (unsigned short)(hu >> 16);
  l = (unsigned short)(fbits(x - __uint_as_float(hu)) >> 16);
}

// f32 LDS tile row stride (floats): bank-start 4r mod 32, 8 consecutive rows
// (lane reindex: lane owns rows {g+8t}) -> 8 distinct bank-quads ->
// conflict-free b128 (r0-verified).
#define FSTRIDE 68
#define FSTRIDE4 17
// psB row stride in shorts: 36 -> 72 B = 18 dwords; 18r mod 32 is distinct for
// all 16 simultaneously-read rows (gcd(18,32)=2, period 16) -> conflict-free
// A-frag b128 reads.
#define PSTRIDE 36

// ---------------------------------------------------------------------------
// Weight split prep.
// ---------------------------------------------------------------------------
__global__ __launch_bounds__(256) void wsplit_kernel(
    const float* __restrict__ W1a, const float* __restrict__ W2a, const float* __restrict__ W3a,
    const float* __restrict__ W1b, const float* __restrict__ W2b, const float* __restrict__ W3b,
    unsigned short* __restrict__ sp)
{
  int idx = blockIdx.x * 256 + threadIdx.x;       // 0..196607
  const int set = idx >= 98304;
  int r = idx - set * 98304;
  unsigned short* base = sp + (size_t)set * 196608;
  const float* src;
  unsigned short *dh, *dl;
  int j;
  if (r < 16384)      { src = set ? W1b : W1a; dh = base;          dl = base + 16384;  j = r; }
  else if (r < 81920) { src = set ? W2b : W2a; dh = base + 32768;  dl = base + 98304;  j = r - 16384; }
  else                { src = set ? W3b : W3a; dh = base + 163840; dl = base + 180224; j = r - 81920; }
  unsigned short h, l;
  splitbf(src[j], h, l);
  dh[j] = h; dl[j] = l;
}

// ---------------------------------------------------------------------------
// V pre-transpose: Vt[b][d][k] = bf16(V[b][k][d]).
// ---------------------------------------------------------------------------
__global__ __launch_bounds__(256) void vtrans_kernel(
    const float* __restrict__ V, unsigned short* __restrict__ Vt)
{
  __shared__ unsigned short t[64][80];
  const int tid = threadIdx.x;
  const int b = blockIdx.y;
  const int k0 = blockIdx.x * 64;
  const float4* V4 = (const float4*)V;
  {
    const int r = tid & 63;
    const int c4 = tid >> 6;
#pragma unroll
    for (int j = 0; j < 4; ++j) {
      float4 f = V4[((size_t)(b * NKK + k0 + r)) * 16 + c4 * 4 + j];
      const int d0 = c4 * 16 + j * 4;
      t[d0 + 0][r] = (unsigned short)(fbits(f.x) >> 16);
      t[d0 + 1][r] = (unsigned short)(fbits(f.y) >> 16);
      t[d0 + 2][r] = (unsigned short)(fbits(f.z) >> 16);
      t[d0 + 3][r] = (unsigned short)(fbits(f.w) >> 16);
    }
  }
  __syncthreads();
  {
    const int d = tid >> 2;
    const int kc = tid & 3;
    uint4 u0 = *(const uint4*)&t[d][kc * 16];
    uint4 u1 = *(const uint4*)&t[d][kc * 16 + 8];
    unsigned short* dst = Vt + ((size_t)(b * 64 + d)) * NKK + k0 + kc * 16;
    *(uint4*)dst = u0;
    *(uint4*)(dst + 8) = u1;
  }
}

// ---------------------------------------------------------------------------
// MLP on MFMA, split-bf16 (hh+lh+hl). 64 tokens/WG, 512 threads (8 waves).
// ---------------------------------------------------------------------------
#define HSTRIDE 264   // shorts; 528B = 132 dwords = 4 mod 32 -> 2-way (free)
__global__ __launch_bounds__(512, 1) void mlpmm_kernel(
    const float* __restrict__ KEY, const float* __restrict__ QUERY,
    const float* __restrict__ B1a, const float* __restrict__ B2a, const float* __restrict__ B3a,
    const float* __restrict__ B1b, const float* __restrict__ B2b, const float* __restrict__ B3b,
    const unsigned short* __restrict__ sp,
    float* __restrict__ Ks, float* __restrict__ Qs, float* __restrict__ Wo)
{
  __shared__ unsigned short Xh[64][72], Xl[64][72];             // 18 KB
  __shared__ unsigned short Hsh[64][HSTRIDE], Hsl[64][HSTRIDE]; // 66 KB
  const int tid = threadIdx.x;
  const int w = tid >> 6;        // 0..7
  const int lane = tid & 63;
  const int l15 = lane & 15;
  const int quad = lane >> 4;

  const int g = blockIdx.x;
  const float* X;
  float* outp;
  int mulx, t0;
  const unsigned short* wb;
  const float *b1, *b2, *b3;
  if (g < 256)      { X = KEY;   outp = Ks; mulx = 1; t0 = g * 64;         wb = sp;          b1 = B1a; b2 = B2a; b3 = B3a; }
  else if (g < 512) { X = QUERY; outp = Qs; mulx = 1; t0 = (g - 256) * 64; wb = sp;          b1 = B1a; b2 = B2a; b3 = B3a; }
  else              { X = QUERY; outp = Wo; mulx = 0; t0 = (g - 512) * 64; wb = sp + 196608; b1 = B1b; b2 = B2b; b3 = B3b; }
  const unsigned short* W1h = wb;
  const unsigned short* W1l = wb + 16384;
  const unsigned short* W2h = wb + 32768;
  const unsigned short* W2l = wb + 98304;
  const unsigned short* W3h = wb + 163840;
  const unsigned short* W3l = wb + 180224;

  // ---- stage X tile (64 rows), split to bf16 h/l ----
  {
    const int t = tid >> 3;
    const int c = (tid & 7) * 8;
    float4 a = *(const float4*)&X[(size_t)(t0 + t) * 64 + c];
    float4 b = *(const float4*)&X[(size_t)(t0 + t) * 64 + c + 4];
    float v[8] = {a.x, a.y, a.z, a.w, b.x, b.y, b.z, b.w};
    unsigned short hs[8], ls[8];
#pragma unroll
    for (int e = 0; e < 8; ++e) splitbf(v[e], hs[e], ls[e]);
    uint4 uh = make_uint4(hs[0] | ((unsigned)hs[1] << 16), hs[2] | ((unsigned)hs[3] << 16),
                          hs[4] | ((unsigned)hs[5] << 16), hs[6] | ((unsigned)hs[7] << 16));
    uint4 ul = make_uint4(ls[0] | ((unsigned)ls[1] << 16), ls[2] | ((unsigned)ls[3] << 16),
                          ls[4] | ((unsigned)ls[5] << 16), ls[6] | ((unsigned)ls[7] << 16));
    *(uint4*)&Xh[t][c] = uh;
    *(uint4*)&Xl[t][c] = ul;
  }
  __syncthreads();

  // ---- layer 1: [64x64] x [64->256] ----
  {
    floatx4 acc[4][2];
#pragma unroll
    for (int nb = 0; nb < 2; ++nb) {
      const float bias = b1[(w * 2 + nb) * 16 + l15];
#pragma unroll
      for (int mb = 0; mb < 4; ++mb) acc[mb][nb] = (floatx4){bias, bias, bias, bias};
    }
#pragma unroll
    for (int kb = 0; kb < 2; ++kb) {
      bf16x8 Ah[4], Al[4];
#pragma unroll
      for (int mb = 0; mb < 4; ++mb) {
        Ah[mb] = *(const bf16x8*)&Xh[mb * 16 + l15][kb * 32 + quad * 8];
        Al[mb] = *(const bf16x8*)&Xl[mb * 16 + l15][kb * 32 + quad * 8];
      }
#pragma unroll
      for (int nb = 0; nb < 2; ++nb) {
        const int n0 = (w * 2 + nb) * 16;
        bf16x8 Bh = *(const bf16x8*)&W1h[(size_t)(n0 + l15) * 64 + kb * 32 + quad * 8];
        bf16x8 Bl = *(const bf16x8*)&W1l[(size_t)(n0 + l15) * 64 + kb * 32 + quad * 8];
#pragma unroll
        for (int mb = 0; mb < 4; ++mb) {
          acc[mb][nb] = __builtin_amdgcn_mfma_f32_16x16x32_bf16(Ah[mb], Bh, acc[mb][nb], 0, 0, 0);
          acc[mb][nb] = __builtin_amdgcn_mfma_f32_16x16x32_bf16(Al[mb], Bh, acc[mb][nb], 0, 0, 0);
          acc[mb][nb] = __builtin_amdgcn_mfma_f32_16x16x32_bf16(Ah[mb], Bl, acc[mb][nb], 0, 0, 0);
        }
      }
    }
#pragma unroll
    for (int mb = 0; mb < 4; ++mb)
#pragma unroll
      for (int nb = 0; nb < 2; ++nb) {
        const int col = (w * 2 + nb) * 16 + l15;
#pragma unroll
        for (int r = 0; r < 4; ++r) {
          const int row = mb * 16 + quad * 4 + r;
          float v = fmaxf(acc[mb][nb][r], 0.0f);
          unsigned short h, l;
          splitbf(v, h, l);
          Hsh[row][col] = h;
          Hsl[row][col] = l;
        }
      }
  }
  __syncthreads();

  // ---- layer 2: [64x256] x [256->256] ----
  {
    floatx4 acc2[4][2];
#pragma unroll
    for (int nb = 0; nb < 2; ++nb) {
      const float bias = b2[(w * 2 + nb) * 16 + l15];
#pragma unroll
      for (int mb = 0; mb < 4; ++mb) acc2[mb][nb] = (floatx4){bias, bias, bias, bias};
    }
#pragma unroll
    for (int kb = 0; kb < 8; ++kb) {
      bf16x8 Ah[4], Al[4];
#pragma unroll
      for (int mb = 0; mb < 4; ++mb) {
        Ah[mb] = *(const bf16x8*)&Hsh[mb * 16 + l15][kb * 32 + quad * 8];
        Al[mb] = *(const bf16x8*)&Hsl[mb * 16 + l15][kb * 32 + quad * 8];
      }
#pragma unroll
      for (int nb = 0; nb < 2; ++nb) {
        const int n0 = (w * 2 + nb) * 16;
        bf16x8 Bh = *(const bf16x8*)&W2h[(size_t)(n0 + l15) * 256 + kb * 32 + quad * 8];
        bf16x8 Bl = *(const bf16x8*)&W2l[(size_t)(n0 + l15) * 256 + kb * 32 + quad * 8];
#pragma unroll
        for (int mb = 0; mb < 4; ++mb) {
          acc2[mb][nb] = __builtin_amdgcn_mfma_f32_16x16x32_bf16(Ah[mb], Bh, acc2[mb][nb], 0, 0, 0);
          acc2[mb][nb] = __builtin_amdgcn_mfma_f32_16x16x32_bf16(Al[mb], Bh, acc2[mb][nb], 0, 0, 0);
          acc2[mb][nb] = __builtin_amdgcn_mfma_f32_16x16x32_bf16(Ah[mb], Bl, acc2[mb][nb], 0, 0, 0);
        }
      }
    }
    __syncthreads();
#pragma unroll
    for (int mb = 0; mb < 4; ++mb)
#pragma unroll
      for (int nb = 0; nb < 2; ++nb) {
        const int col = (w * 2 + nb) * 16 + l15;
#pragma unroll
        for (int r = 0; r < 4; ++r) {
          const int row = mb * 16 + quad * 4 + r;
          float v = fmaxf(acc2[mb][nb][r], 0.0f);
          unsigned short h, l;
          splitbf(v, h, l);
          Hsh[row][col] = h;
          Hsl[row][col] = l;
        }
      }
  }
  __syncthreads();

  // ---- layer 3: [64x256] x [256->64] ----
  {
    const int mp = (w >> 2) * 2;
    const int n0 = (w & 3) * 16;
    const float bias = b3[n0 + l15];
    floatx4 acc3[2];
#pragma unroll
    for (int m = 0; m < 2; ++m) acc3[m] = (floatx4){bias, bias, bias, bias};
#pragma unroll
    for (int kb = 0; kb < 8; ++kb) {
      bf16x8 Ah[2], Al[2];
#pragma unroll
      for (int m = 0; m < 2; ++m) {
        Ah[m] = *(const bf16x8*)&Hsh[(mp + m) * 16 + l15][kb * 32 + quad * 8];
        Al[m] = *(const bf16x8*)&Hsl[(mp + m) * 16 + l15][kb * 32 + quad * 8];
      }
      bf16x8 Bh = *(const bf16x8*)&W3h[(size_t)(n0 + l15) * 256 + kb * 32 + quad * 8];
      bf16x8 Bl = *(const bf16x8*)&W3l[(size_t)(n0 + l15) * 256 + kb * 32 + quad * 8];
#pragma unroll
      for (int m = 0; m < 2; ++m) {
        acc3[m] = __builtin_amdgcn_mfma_f32_16x16x32_bf16(Ah[m], Bh, acc3[m], 0, 0, 0);
        acc3[m] = __builtin_amdgcn_mfma_f32_16x16x32_bf16(Al[m], Bh, acc3[m], 0, 0, 0);
        acc3[m] = __builtin_amdgcn_mfma_f32_16x16x32_bf16(Ah[m], Bl, acc3[m], 0, 0, 0);
      }
    }
#pragma unroll
    for (int m = 0; m < 2; ++m)
#pragma unroll
      for (int r = 0; r < 4; ++r) {
        const int row = (mp + m) * 16 + quad * 4 + r;
        const int col = n0 + l15;
        float v = acc3[m][r];
        if (mulx) v *= (bf2f(Xh[row][col]) + bf2f(Xl[row][col]));
        outp[(size_t)(t0 + row) * 64 + col] = v;
      }
  }
}

// ---------------------------------------------------------------------------
// Flash attention over L1-distance scores, P.V on MFMA.
// Round-14 resubmit (round-6 bench was an infra failure; no data).
// EXACT round-8 geometry (52 KB LDS, 3 blocks/CU, 32q blocks, z=3
// wave-private 352/320-key slices, 1536 blocks = 2 rounds of 768 resident)
// -- the ONLY configuration in 6 rounds with L2 reuse intact (FETCH 72 MB)
// and best time (attn 325 us). Two in-loop cuts, zero geometry changes:
//  * qc register cache: Q frags for dc=0,1 (8 floatx4 = 32 VGPR, total
//    ~116 < the 128 occupancy cliff) are loop-invariant -> drop 8 of 128
//    score ds_read_b128 per iter.
//  * conditional rescale (exact): when no row's max improved this iter
//    (ballot), every a_row == 1.0 exactly -> skip abA write + 2 b128 abA
//    reads + 16 v_pk_mul acc rescale. Bitwise-identical output.
// ---------------------------------------------------------------------------
template <bool PARTIAL>
__global__ __launch_bounds__(256, 3) void attn_kernel(
    const float* __restrict__ Ksg, const float* __restrict__ Qsg,
    const unsigned short* __restrict__ Vtg, const float* __restrict__ Wog,
    float* __restrict__ outp,
    float* __restrict__ Pm, float* __restrict__ Pl, float* __restrict__ PO)
{
  __shared__ float qsA[32 * FSTRIDE];              // 8704 B
  __shared__ float ksA[4][32 * FSTRIDE];           // 34816 B; reused as O-merge buf
  __shared__ unsigned short psB[4][32 * PSTRIDE];  // 9216 B; epilogue: m/l overlay
  __shared__ float abA[4][32];                     // 512 B
  // total 53248 B = 52 KB exactly -> 3 blocks/CU

  const int tid  = threadIdx.x;
  const int w    = tid >> 6;
  const int lane = tid & 63;
  const int lq   = lane >> 3;
  const int lk   = lane & 7;
  const int l15  = lane & 15;
  const int quad = lane >> 4;
  const int b    = blockIdx.y;
  const int qt   = blockIdx.x * 32;

  {
    const int row = tid >> 3;
    const int c0  = (tid & 7) * 2;
    const float4* Q4 = (const float4*)Qsg;
    float4 g0 = Q4[(size_t)(b * NQQ + qt + row) * 16 + c0];
    float4 g1 = Q4[(size_t)(b * NQQ + qt + row) * 16 + c0 + 1];
    *(float4*)&qsA[row * FSTRIDE + c0 * 4]     = g0;
    *(float4*)&qsA[row * FSTRIDE + c0 * 4 + 4] = g1;
  }
  __syncthreads();

  float m_i[4], l_i[4];
  floatx4 acc[2][4];
#pragma unroll
  for (int i = 0; i < 4; ++i) { m_i[i] = -3.0e38f; l_i[i] = 0.0f; }
#pragma unroll
  for (int mb = 0; mb < 2; ++mb)
#pragma unroll
    for (int nb = 0; nb < 4; ++nb)
#pragma unroll
      for (int r = 0; r < 4; ++r) acc[mb][nb][r] = 0.0f;

  int kstart, iters;
  if (PARTIAL) {
    const int slice = blockIdx.z * 4 + w;          // 0..11
    iters  = (slice < 8) ? 11 : 10;
    kstart = (slice < 8) ? slice * 352 : 2816 + (slice - 8) * 320;
  } else {
    iters  = 32;
    kstart = w * 1024;
  }
  const float4* K4 = (const float4*)Ksg;
  const float NEG_HALF_LOG2E = -0.72134752044448170f;  // -0.5*log2(e)

  const int krow = (lane >> 4);
  const int kci  = lane & 15;

  // V B-frag global base: lane (quad,l15) of frag nb reads
  // Vt[b][nb*16+l15][k=kstart+it*32+quad*8 .. +8] (16B, L2-resident).
  const unsigned short* vg0 = Vtg + ((size_t)b * 64 + l15) * NKK + kstart + quad * 8;

  float4 kpre[8];
  uint4 vtpre[4];
#pragma unroll
  for (int c = 0; c < 8; ++c)
    kpre[c] = K4[(size_t)(b * NKK + kstart + c * 4 + krow) * 16 + kci];
#pragma unroll
  for (int nb = 0; nb < 4; ++nb)
    vtpre[nb] = *(const uint4*)(vg0 + (size_t)nb * 16 * NKK);

  const floatx4* qb = (const floatx4*)&qsA[lq * FSTRIDE];
  const floatx4* kb = (const floatx4*)&ksA[w][lk * FSTRIDE];

  // ---- loop-invariant Q fragment cache for dc = 0,1 (32 VGPRs) ----
  floatx4 qc[4][2];
#pragma unroll
  for (int i = 0; i < 4; ++i) {
    qc[i][0] = qb[i * (8 * FSTRIDE4)];
    qc[i][1] = qb[i * (8 * FSTRIDE4) + 1];
  }

  for (int it = 0; it < iters; ++it) {
    // ---- store prefetched K tile -> LDS (wave-private, no barrier) ----
#pragma unroll
    for (int c = 0; c < 8; ++c)
      *(float4*)&ksA[w][(c * 4 + krow) * FSTRIDE + kci * 4] = kpre[c];

    // ---- prefetch next K tile ----
    {
      const int itn = (it + 1 < iters) ? it + 1 : it;
#pragma unroll
      for (int c = 0; c < 8; ++c)
        kpre[c] = K4[(size_t)(b * NKK + kstart + itn * 32 + c * 4 + krow) * 16 + kci];
    }

    // ---- score: s[i][j] = sum_d |Ks[lk+8j] - Qs[lq+8i]|, 1.5 VALU/dim ----
    float s[4][4];
#pragma unroll
    for (int i = 0; i < 4; ++i)
#pragma unroll
      for (int j = 0; j < 4; ++j) s[i][j] = 0.0f;

#pragma unroll
    for (int dc = 0; dc < 16; ++dc) {
      floatx4 qv[4], kv[4];
#pragma unroll
      for (int i = 0; i < 4; ++i) {
        if (dc < 2) qv[i] = qc[i][dc];
        else        qv[i] = qb[i * (8 * FSTRIDE4) + dc];
      }
#pragma unroll
      for (int j = 0; j < 4; ++j) kv[j] = kb[j * (8 * FSTRIDE4) + dc];
#pragma unroll
      for (int i = 0; i < 4; ++i) {
        const floatx2 qlo = qv[i].lo, qhi = qv[i].hi;
#pragma unroll
        for (int j = 0; j < 4; ++j) {
          floatx2 d0 = pk_sub(qlo, kv[j].lo);
          floatx2 d1 = pk_sub(qhi, kv[j].hi);
          s[i][j] += __builtin_fabsf(d0.x);
          s[i][j] += __builtin_fabsf(d0.y);
          s[i][j] += __builtin_fabsf(d1.x);
          s[i][j] += __builtin_fabsf(d1.y);
        }
      }
    }

    // ---- online softmax (base-2); row max via min(s); l per-lane ----
    float a_row[4];
    float impmax = -1.0f;
#pragma unroll
    for (int i = 0; i < 4; ++i) {
      float smin = fminf(fminf(s[i][0], s[i][1]), fminf(s[i][2], s[i][3]));
      smin = fminf(smin, __shfl_xor(smin, 1));
      smin = fminf(smin, __shfl_xor(smin, 2));
      smin = fminf(smin, __shfl_xor(smin, 4));
      const float tmax = smin * smin * NEG_HALF_LOG2E;
      const float mo = m_i[i];
      const float mn = fmaxf(mo, tmax);
      a_row[i] = fexp2(mo - mn);
      m_i[i] = mn;
      impmax = fmaxf(impmax, mn - mo);
      float ps = 0.0f;
#pragma unroll
      for (int j = 0; j < 4; ++j) {
        const float sv = s[i][j];
        const float e = fexp2(fmaf(sv * NEG_HALF_LOG2E, sv, -mn));
        ps += e;
        psB[w][(lq + 8 * i) * PSTRIDE + lk + 8 * j] = (unsigned short)(fbits(e) >> 16);
      }
      l_i[i] = fmaf(l_i[i], a_row[i], ps);
    }
    // uniform across the wave: did ANY row of ANY lane improve its max?
    const bool resc = (__ballot(impmax > 0.0f) != 0ull);
    if (resc && lk == 0) {
#pragma unroll
      for (int i = 0; i < 4; ++i) abA[w][lq + 8 * i] = a_row[i];
    }

    // ---- P.V on MFMA (B-frags straight from prefetched registers) ----
    {
      bf16x8 afrag[2];
#pragma unroll
      for (int mb = 0; mb < 2; ++mb)
        afrag[mb] = *(const bf16x8*)&psB[w][(mb * 16 + l15) * PSTRIDE + quad * 8];

      if (resc) {
        const floatx4 arv0 = *(const floatx4*)&abA[w][quad * 4];
        const floatx4 arv1 = *(const floatx4*)&abA[w][16 + quad * 4];
#pragma unroll
        for (int nb = 0; nb < 4; ++nb) {
          acc[0][nb] *= arv0;
          acc[1][nb] *= arv1;
        }
      }
#pragma unroll
      for (int nb = 0; nb < 4; ++nb) {
        bf16x8 bfrag = __builtin_bit_cast(bf16x8, vtpre[nb]);
        acc[0][nb] = __builtin_amdgcn_mfma_f32_16x16x32_bf16(afrag[0], bfrag, acc[0][nb], 0, 0, 0);
        acc[1][nb] = __builtin_amdgcn_mfma_f32_16x16x32_bf16(afrag[1], bfrag, acc[1][nb], 0, 0, 0);
      }
    }

    // ---- prefetch next V tile (used next iter; full iter of latency slack) ----
    {
      const int itn = (it + 1 < iters) ? it + 1 : it;
#pragma unroll
      for (int nb = 0; nb < 4; ++nb)
        vtpre[nb] = *(const uint4*)(vg0 + (size_t)nb * 16 * NKK + itn * 32);
    }
  }

  // ---- epilogue: reduce l across lk; publish m,l (overlay on psB[w]) + O ----
#pragma unroll
  for (int i = 0; i < 4; ++i) {
    float l = l_i[i];
    l += __shfl_xor(l, 1);
    l += __shfl_xor(l, 2);
    l += __shfl_xor(l, 4);
    l_i[i] = l;
  }
  float* ovl = (float*)&psB[w][0];   // psB[w] dead after last P.V (wave-private)
  if (lk == 0) {
#pragma unroll
    for (int i = 0; i < 4; ++i) {
      ovl[lq + 8 * i]      = m_i[i];
      ovl[32 + lq + 8 * i] = l_i[i];
    }
  }
#pragma unroll
  for (int mb = 0; mb < 2; ++mb)
#pragma unroll
    for (int nb = 0; nb < 4; ++nb)
#pragma unroll
      for (int r = 0; r < 4; ++r)
        ksA[w][(mb * 16 + quad * 4 + r) * 64 + nb * 16 + l15] = acc[mb][nb][r];
  __syncthreads();

  {
    const int q = tid >> 3;
    const int dbase = (tid & 7) * 8;
    const float m0 = ((const float*)&psB[0][0])[q];
    const float m1 = ((const float*)&psB[1][0])[q];
    const float m2 = ((const float*)&psB[2][0])[q];
    const float m3 = ((const float*)&psB[3][0])[q];
    const float M = fmaxf(fmaxf(m0, m1), fmaxf(m2, m3));
    const float s0 = fexp2(m0 - M), s1 = fexp2(m1 - M);
    const float s2v = fexp2(m2 - M), s3 = fexp2(m3 - M);
    const float L = ((const float*)&psB[0][0])[32 + q] * s0 +
                    ((const float*)&psB[1][0])[32 + q] * s1 +
                    ((const float*)&psB[2][0])[32 + q] * s2v +
                    ((const float*)&psB[3][0])[32 + q] * s3;
    if (PARTIAL) {
      const size_t p = (size_t)(blockIdx.z * 4 + b) * 128 + blockIdx.x;
      if (dbase == 0) { Pm[p * 32 + q] = M; Pl[p * 32 + q] = L; }
      float* dst = PO + p * 2048 + q * 64 + dbase;
#pragma unroll
      for (int c = 0; c < 8; ++c) {
        const int d = dbase + c;
        dst[c] = s0 * ksA[0][q * 64 + d] + s1 * ksA[1][q * 64 + d] +
                 s2v * ksA[2][q * 64 + d] + s3 * ksA[3][q * 64 + d];
      }
    } else {
      const float rL = 1.0f / L;
      const size_t gbase = (size_t)(b * NQQ + qt + q) * 64 + dbase;
#pragma unroll
      for (int c = 0; c < 8; ++c) {
        const int d = dbase + c;
        float o = s0 * ksA[0][q * 64 + d] + s1 * ksA[1][q * 64 + d] +
                  s2v * ksA[2][q * 64 + d] + s3 * ksA[3][q * 64 + d];
        outp[gbase + c] = o * rL * Wog[gbase + c];
      }
    }
  }
}

// ---------------------------------------------------------------------------
// Merge the 3 key-split partials: out = sum_s(w_s O_s)/L * Wo.
// ---------------------------------------------------------------------------
__global__ __launch_bounds__(256) void amerge_kernel(
    const float* __restrict__ Pm, const float* __restrict__ Pl,
    const float* __restrict__ PO, const float* __restrict__ Wog,
    float* __restrict__ outp)
{
  const int tid = threadIdx.x;
  const int qt = blockIdx.x;
  const int b = blockIdx.y;
  const int q = tid >> 3;
  const int dbase = (tid & 7) * 8;
  size_t p[3];
  float mv[3], lv[3];
#pragma unroll
  for (int s = 0; s < 3; ++s) {
    p[s] = (size_t)(s * 4 + b) * 128 + qt;
    mv[s] = Pm[p[s] * 32 + q];
    lv[s] = Pl[p[s] * 32 + q];
  }
  const float M = fmaxf(fmaxf(mv[0], mv[1]), mv[2]);
  float wsum = 0.0f, wgt[3];
#pragma unroll
  for (int s = 0; s < 3; ++s) { wgt[s] = fexp2(mv[s] - M); wsum += wgt[s] * lv[s]; }
  const float rL = 1.0f / wsum;
  const size_t g = ((size_t)b * NQQ + qt * 32 + q) * 64 + dbase;
#pragma unroll
  for (int c = 0; c < 8; ++c) {
    float o = 0.0f;
#pragma unroll
    for (int s = 0; s < 3; ++s) o += wgt[s] * PO[p[s] * 2048 + q * 64 + dbase + c];
    outp[g + c] = o * rL * Wog[g + c];
  }
}

// ---------------------------------------------------------------------------
extern "C" void kernel_launch(void* const* d_in, const int* in_sizes, int n_in,
                              void* d_out, int out_size, void* d_ws, size_t ws_size,
                              hipStream_t stream) {
  (void)in_sizes; (void)n_in; (void)out_size;
  const float* KEY   = (const float*)d_in[0];
  const float* VALUE = (const float*)d_in[1];
  const float* QUERY = (const float*)d_in[2];
  const float* W1w = (const float*)d_in[3];
  const float* W1b = (const float*)d_in[4];
  const float* W2w = (const float*)d_in[5];
  const float* W2b = (const float*)d_in[6];
  const float* W3w = (const float*)d_in[7];
  const float* W3b = (const float*)d_in[8];
  const float* Wo1w = (const float*)d_in[9];
  const float* Wo1b = (const float*)d_in[10];
  const float* Wo2w = (const float*)d_in[11];
  const float* Wo2b = (const float*)d_in[12];
  const float* Wo3w = (const float*)d_in[13];
  const float* Wo3b = (const float*)d_in[14];

  float* ws = (float*)d_ws;
  const size_t tsz = (size_t)B_DIM * NKK * DD;  // 1,048,576 floats
  float* Ks = ws;
  float* Qs = ws + tsz;
  float* Wo = ws + 2 * tsz;
  unsigned short* Vtg = (unsigned short*)(ws + 3 * tsz);  // tsz ushorts (2 MB)
  unsigned short* sp  = Vtg + tsz;                        // 2x196608 ushorts
  float* Pm = ws + 3 * tsz + tsz / 2 + 196608;            // partial maxes (12x128x32)
  float* Pl = Pm + 49152;
  float* PO = Pl + 49152;                                 // 12x128x2048 floats
  float* outf = (float*)d_out;

  const size_t ws_need = (size_t)(3 * tsz + tsz / 2 + 196608 + 2 * 49152 + 3145728) * 4;
  const bool partial = ws_size >= ws_need;   // deterministic across calls

  wsplit_kernel<<<dim3(768), 256, 0, stream>>>(W1w, W2w, W3w, Wo1w, Wo2w, Wo3w, sp);
  vtrans_kernel<<<dim3(NKK / 64, B_DIM), 256, 0, stream>>>(VALUE, Vtg);
  mlpmm_kernel<<<dim3(768), 512, 0, stream>>>(
      KEY, QUERY, W1b, W2b, W3b, Wo1b, Wo2b, Wo3b, sp, Ks, Qs, Wo);
  if (partial) {
    attn_kernel<true><<<dim3(NQQ / 32, B_DIM, 3), 256, 0, stream>>>(
        Ks, Qs, Vtg, Wo, outf, Pm, Pl, PO);
    amerge_kernel<<<dim3(NQQ / 32, B_DIM), 256, 0, stream>>>(Pm, Pl, PO, Wo, outf);
  } else {
    attn_kernel<false><<<dim3(NQQ / 32, B_DIM, 1), 256, 0, stream>>>(
        Ks, Qs, Vtg, Wo, outf, Pm, Pl, PO);
  }
}

// Round 8
// 413.083 us; speedup vs baseline: 1.1506x; 1.0834x over previous
//
#include <hip/hip_runtime.h>
#include <hip/hip_bf16.h>
#include <stdint.h>

#define B_DIM 4
#define NKK 4096
#define NQQ 4096
#define DD 64
#define HH 256

typedef __attribute__((ext_vector_type(4))) float floatx4;
typedef __attribute__((ext_vector_type(2))) float floatx2;
typedef __attribute__((ext_vector_type(8))) short bf16x8;

__device__ __forceinline__ float fexp2(float x) { return __builtin_amdgcn_exp2f(x); }
__device__ __forceinline__ unsigned fbits(float x) { return __float_as_uint(x); }
__device__ __forceinline__ float bf2f(unsigned short u) { return __uint_as_float(((unsigned)u) << 16); }

// a - b on both packed halves in ONE VOP3P instruction (gfx950 has
// v_pk_add_f32 but no packed f32 max/abs -- abs lives on the consumer's
// input modifier).
__device__ __forceinline__ floatx2 pk_sub(floatx2 a, floatx2 b) {
  floatx2 d;
  asm("v_pk_add_f32 %0, %1, %2 neg_lo:[0,1] neg_hi:[0,1]" : "=v"(d) : "v"(a), "v"(b));
  return d;
}

// round-to-nearest-even split: x = h + l, h/l bf16, rel err ~2^-17
__device__ __forceinline__ void splitbf(float x, unsigned short& h, unsigned short& l) {
  unsigned u = fbits(x);
  unsigned hu = (u + 0x7fff + ((u >> 16) & 1)) & 0xffff0000u;
  h = (unsigned short)(hu >> 16);
  l = (unsigned short)(fbits(x - __uint_as_float(hu)) >> 16);
}

// f32 LDS tile row stride (floats): bank-start 4r mod 32, 8 consecutive rows
// (lane reindex: lane owns rows {g+8t}) -> 8 distinct bank-quads ->
// conflict-free b128 (verified round 4: 33.9M -> 2.85M conflicts).
#define FSTRIDE 68
#define FSTRIDE4 17
// psB row stride in shorts: 36 -> 72 B = 18 dwords; 18r mod 32 is distinct for
// all 16 simultaneously-read rows (gcd(18,32)=2, period 16) -> conflict-free
// A-frag b128 reads. 40->36 saves exactly 1 KB -> LDS total 52 KB.
#define PSTRIDE 36

// ---------------------------------------------------------------------------
// Weight split prep.
// ---------------------------------------------------------------------------
__global__ __launch_bounds__(256) void wsplit_kernel(
    const float* __restrict__ W1a, const float* __restrict__ W2a, const float* __restrict__ W3a,
    const float* __restrict__ W1b, const float* __restrict__ W2b, const float* __restrict__ W3b,
    unsigned short* __restrict__ sp)
{
  int idx = blockIdx.x * 256 + threadIdx.x;       // 0..196607
  const int set = idx >= 98304;
  int r = idx - set * 98304;
  unsigned short* base = sp + (size_t)set * 196608;
  const float* src;
  unsigned short *dh, *dl;
  int j;
  if (r < 16384)      { src = set ? W1b : W1a; dh = base;          dl = base + 16384;  j = r; }
  else if (r < 81920) { src = set ? W2b : W2a; dh = base + 32768;  dl = base + 98304;  j = r - 16384; }
  else                { src = set ? W3b : W3a; dh = base + 163840; dl = base + 180224; j = r - 81920; }
  unsigned short h, l;
  splitbf(src[j], h, l);
  dh[j] = h; dl[j] = l;
}

// ---------------------------------------------------------------------------
// V pre-transpose: Vt[b][d][k] = bf16(V[b][k][d]).
// ---------------------------------------------------------------------------
__global__ __launch_bounds__(256) void vtrans_kernel(
    const float* __restrict__ V, unsigned short* __restrict__ Vt)
{
  __shared__ unsigned short t[64][80];
  const int tid = threadIdx.x;
  const int b = blockIdx.y;
  const int k0 = blockIdx.x * 64;
  const float4* V4 = (const float4*)V;
  {
    const int r = tid & 63;
    const int c4 = tid >> 6;
#pragma unroll
    for (int j = 0; j < 4; ++j) {
      float4 f = V4[((size_t)(b * NKK + k0 + r)) * 16 + c4 * 4 + j];
      const int d0 = c4 * 16 + j * 4;
      t[d0 + 0][r] = (unsigned short)(fbits(f.x) >> 16);
      t[d0 + 1][r] = (unsigned short)(fbits(f.y) >> 16);
      t[d0 + 2][r] = (unsigned short)(fbits(f.z) >> 16);
      t[d0 + 3][r] = (unsigned short)(fbits(f.w) >> 16);
    }
  }
  __syncthreads();
  {
    const int d = tid >> 2;
    const int kc = tid & 3;
    uint4 u0 = *(const uint4*)&t[d][kc * 16];
    uint4 u1 = *(const uint4*)&t[d][kc * 16 + 8];
    unsigned short* dst = Vt + ((size_t)(b * 64 + d)) * NKK + k0 + kc * 16;
    *(uint4*)dst = u0;
    *(uint4*)(dst + 8) = u1;
  }
}

// ---------------------------------------------------------------------------
// MLP on MFMA, split-bf16 (hh+lh+hl). 64 tokens/WG, 512 threads (8 waves).
// ---------------------------------------------------------------------------
#define HSTRIDE 264   // shorts; 528B = 132 dwords = 4 mod 32 -> 2-way (free)
__global__ __launch_bounds__(512, 1) void mlpmm_kernel(
    const float* __restrict__ KEY, const float* __restrict__ QUERY,
    const float* __restrict__ B1a, const float* __restrict__ B2a, const float* __restrict__ B3a,
    const float* __restrict__ B1b, const float* __restrict__ B2b, const float* __restrict__ B3b,
    const unsigned short* __restrict__ sp,
    float* __restrict__ Ks, float* __restrict__ Qs, float* __restrict__ Wo)
{
  __shared__ unsigned short Xh[64][72], Xl[64][72];             // 18 KB
  __shared__ unsigned short Hsh[64][HSTRIDE], Hsl[64][HSTRIDE]; // 66 KB
  const int tid = threadIdx.x;
  const int w = tid >> 6;        // 0..7
  const int lane = tid & 63;
  const int l15 = lane & 15;
  const int quad = lane >> 4;

  const int g = blockIdx.x;
  const float* X;
  float* outp;
  int mulx, t0;
  const unsigned short* wb;
  const float *b1, *b2, *b3;
  if (g < 256)      { X = KEY;   outp = Ks; mulx = 1; t0 = g * 64;         wb = sp;          b1 = B1a; b2 = B2a; b3 = B3a; }
  else if (g < 512) { X = QUERY; outp = Qs; mulx = 1; t0 = (g - 256) * 64; wb = sp;          b1 = B1a; b2 = B2a; b3 = B3a; }
  else              { X = QUERY; outp = Wo; mulx = 0; t0 = (g - 512) * 64; wb = sp + 196608; b1 = B1b; b2 = B2b; b3 = B3b; }
  const unsigned short* W1h = wb;
  const unsigned short* W1l = wb + 16384;
  const unsigned short* W2h = wb + 32768;
  const unsigned short* W2l = wb + 98304;
  const unsigned short* W3h = wb + 163840;
  const unsigned short* W3l = wb + 180224;

  // ---- stage X tile (64 rows), split to bf16 h/l ----
  {
    const int t = tid >> 3;
    const int c = (tid & 7) * 8;
    float4 a = *(const float4*)&X[(size_t)(t0 + t) * 64 + c];
    float4 b = *(const float4*)&X[(size_t)(t0 + t) * 64 + c + 4];
    float v[8] = {a.x, a.y, a.z, a.w, b.x, b.y, b.z, b.w};
    unsigned short hs[8], ls[8];
#pragma unroll
    for (int e = 0; e < 8; ++e) splitbf(v[e], hs[e], ls[e]);
    uint4 uh = make_uint4(hs[0] | ((unsigned)hs[1] << 16), hs[2] | ((unsigned)hs[3] << 16),
                          hs[4] | ((unsigned)hs[5] << 16), hs[6] | ((unsigned)hs[7] << 16));
    uint4 ul = make_uint4(ls[0] | ((unsigned)ls[1] << 16), ls[2] | ((unsigned)ls[3] << 16),
                          ls[4] | ((unsigned)ls[5] << 16), ls[6] | ((unsigned)ls[7] << 16));
    *(uint4*)&Xh[t][c] = uh;
    *(uint4*)&Xl[t][c] = ul;
  }
  __syncthreads();

  // ---- layer 1: [64x64] x [64->256] ----
  {
    floatx4 acc[4][2];
#pragma unroll
    for (int nb = 0; nb < 2; ++nb) {
      const float bias = b1[(w * 2 + nb) * 16 + l15];
#pragma unroll
      for (int mb = 0; mb < 4; ++mb) acc[mb][nb] = (floatx4){bias, bias, bias, bias};
    }
#pragma unroll
    for (int kb = 0; kb < 2; ++kb) {
      bf16x8 Ah[4], Al[4];
#pragma unroll
      for (int mb = 0; mb < 4; ++mb) {
        Ah[mb] = *(const bf16x8*)&Xh[mb * 16 + l15][kb * 32 + quad * 8];
        Al[mb] = *(const bf16x8*)&Xl[mb * 16 + l15][kb * 32 + quad * 8];
      }
#pragma unroll
      for (int nb = 0; nb < 2; ++nb) {
        const int n0 = (w * 2 + nb) * 16;
        bf16x8 Bh = *(const bf16x8*)&W1h[(size_t)(n0 + l15) * 64 + kb * 32 + quad * 8];
        bf16x8 Bl = *(const bf16x8*)&W1l[(size_t)(n0 + l15) * 64 + kb * 32 + quad * 8];
#pragma unroll
        for (int mb = 0; mb < 4; ++mb) {
          acc[mb][nb] = __builtin_amdgcn_mfma_f32_16x16x32_bf16(Ah[mb], Bh, acc[mb][nb], 0, 0, 0);
          acc[mb][nb] = __builtin_amdgcn_mfma_f32_16x16x32_bf16(Al[mb], Bh, acc[mb][nb], 0, 0, 0);
          acc[mb][nb] = __builtin_amdgcn_mfma_f32_16x16x32_bf16(Ah[mb], Bl, acc[mb][nb], 0, 0, 0);
        }
      }
    }
#pragma unroll
    for (int mb = 0; mb < 4; ++mb)
#pragma unroll
      for (int nb = 0; nb < 2; ++nb) {
        const int col = (w * 2 + nb) * 16 + l15;
#pragma unroll
        for (int r = 0; r < 4; ++r) {
          const int row = mb * 16 + quad * 4 + r;
          float v = fmaxf(acc[mb][nb][r], 0.0f);
          unsigned short h, l;
          splitbf(v, h, l);
          Hsh[row][col] = h;
          Hsl[row][col] = l;
        }
      }
  }
  __syncthreads();

  // ---- layer 2: [64x256] x [256->256] ----
  {
    floatx4 acc2[4][2];
#pragma unroll
    for (int nb = 0; nb < 2; ++nb) {
      const float bias = b2[(w * 2 + nb) * 16 + l15];
#pragma unroll
      for (int mb = 0; mb < 4; ++mb) acc2[mb][nb] = (floatx4){bias, bias, bias, bias};
    }
#pragma unroll
    for (int kb = 0; kb < 8; ++kb) {
      bf16x8 Ah[4], Al[4];
#pragma unroll
      for (int mb = 0; mb < 4; ++mb) {
        Ah[mb] = *(const bf16x8*)&Hsh[mb * 16 + l15][kb * 32 + quad * 8];
        Al[mb] = *(const bf16x8*)&Hsl[mb * 16 + l15][kb * 32 + quad * 8];
      }
#pragma unroll
      for (int nb = 0; nb < 2; ++nb) {
        const int n0 = (w * 2 + nb) * 16;
        bf16x8 Bh = *(const bf16x8*)&W2h[(size_t)(n0 + l15) * 256 + kb * 32 + quad * 8];
        bf16x8 Bl = *(const bf16x8*)&W2l[(size_t)(n0 + l15) * 256 + kb * 32 + quad * 8];
#pragma unroll
        for (int mb = 0; mb < 4; ++mb) {
          acc2[mb][nb] = __builtin_amdgcn_mfma_f32_16x16x32_bf16(Ah[mb], Bh, acc2[mb][nb], 0, 0, 0);
          acc2[mb][nb] = __builtin_amdgcn_mfma_f32_16x16x32_bf16(Al[mb], Bh, acc2[mb][nb], 0, 0, 0);
          acc2[mb][nb] = __builtin_amdgcn_mfma_f32_16x16x32_bf16(Ah[mb], Bl, acc2[mb][nb], 0, 0, 0);
        }
      }
    }
    __syncthreads();
#pragma unroll
    for (int mb = 0; mb < 4; ++mb)
#pragma unroll
      for (int nb = 0; nb < 2; ++nb) {
        const int col = (w * 2 + nb) * 16 + l15;
#pragma unroll
        for (int r = 0; r < 4; ++r) {
          const int row = mb * 16 + quad * 4 + r;
          float v = fmaxf(acc2[mb][nb][r], 0.0f);
          unsigned short h, l;
          splitbf(v, h, l);
          Hsh[row][col] = h;
          Hsl[row][col] = l;
        }
      }
  }
  __syncthreads();

  // ---- layer 3: [64x256] x [256->64] ----
  {
    const int mp = (w >> 2) * 2;
    const int n0 = (w & 3) * 16;
    const float bias = b3[n0 + l15];
    floatx4 acc3[2];
#pragma unroll
    for (int m = 0; m < 2; ++m) acc3[m] = (floatx4){bias, bias, bias, bias};
#pragma unroll
    for (int kb = 0; kb < 8; ++kb) {
      bf16x8 Ah[2], Al[2];
#pragma unroll
      for (int m = 0; m < 2; ++m) {
        Ah[m] = *(const bf16x8*)&Hsh[(mp + m) * 16 + l15][kb * 32 + quad * 8];
        Al[m] = *(const bf16x8*)&Hsl[(mp + m) * 16 + l15][kb * 32 + quad * 8];
      }
      bf16x8 Bh = *(const bf16x8*)&W3h[(size_t)(n0 + l15) * 256 + kb * 32 + quad * 8];
      bf16x8 Bl = *(const bf16x8*)&W3l[(size_t)(n0 + l15) * 256 + kb * 32 + quad * 8];
#pragma unroll
      for (int m = 0; m < 2; ++m) {
        acc3[m] = __builtin_amdgcn_mfma_f32_16x16x32_bf16(Ah[m], Bh, acc3[m], 0, 0, 0);
        acc3[m] = __builtin_amdgcn_mfma_f32_16x16x32_bf16(Al[m], Bh, acc3[m], 0, 0, 0);
        acc3[m] = __builtin_amdgcn_mfma_f32_16x16x32_bf16(Ah[m], Bl, acc3[m], 0, 0, 0);
      }
    }
#pragma unroll
    for (int m = 0; m < 2; ++m)
#pragma unroll
      for (int r = 0; r < 4; ++r) {
        const int row = (mp + m) * 16 + quad * 4 + r;
        const int col = n0 + l15;
        float v = acc3[m][r];
        if (mulx) v *= (bf2f(Xh[row][col]) + bf2f(Xl[row][col]));
        outp[(size_t)(t0 + row) * 64 + col] = v;
      }
  }
}

// ---------------------------------------------------------------------------
// Flash attention over L1-distance scores, P.V on MFMA.
// Round-16 (final consolidation): EXACT round-8/round-0 kernel, both round-14
// micro-opts reverted. Evidence: qcache was rematerialized by the compiler
// (VGPR stayed 84 -> no DS saved), conditional rescale's ballot overhead ~=
// its savings (attn 325 -> 339). Every 3-blocks/CU variant lands 325-340 us
// regardless of FETCH (72-360 MB) or DS count (-25% in r12); 4/CU variants
// are strictly worse (385-430). This source is the measured optimum (412.6
// us total) -- restored verbatim.
// ---------------------------------------------------------------------------
template <bool PARTIAL>
__global__ __launch_bounds__(256, 3) void attn_kernel(
    const float* __restrict__ Ksg, const float* __restrict__ Qsg,
    const unsigned short* __restrict__ Vtg, const float* __restrict__ Wog,
    float* __restrict__ outp,
    float* __restrict__ Pm, float* __restrict__ Pl, float* __restrict__ PO)
{
  __shared__ float qsA[32 * FSTRIDE];              // 8704 B
  __shared__ float ksA[4][32 * FSTRIDE];           // 34816 B; reused as O-merge buf
  __shared__ unsigned short psB[4][32 * PSTRIDE];  // 9216 B; epilogue: m/l overlay
  __shared__ float abA[4][32];                     // 512 B
  // total 53248 B = 52 KB exactly -> 3 blocks/CU

  const int tid  = threadIdx.x;
  const int w    = tid >> 6;
  const int lane = tid & 63;
  const int lq   = lane >> 3;
  const int lk   = lane & 7;
  const int l15  = lane & 15;
  const int quad = lane >> 4;
  const int b    = blockIdx.y;
  const int qt   = blockIdx.x * 32;

  {
    const int row = tid >> 3;
    const int c0  = (tid & 7) * 2;
    const float4* Q4 = (const float4*)Qsg;
    float4 g0 = Q4[(size_t)(b * NQQ + qt + row) * 16 + c0];
    float4 g1 = Q4[(size_t)(b * NQQ + qt + row) * 16 + c0 + 1];
    *(float4*)&qsA[row * FSTRIDE + c0 * 4]     = g0;
    *(float4*)&qsA[row * FSTRIDE + c0 * 4 + 4] = g1;
  }
  __syncthreads();

  float m_i[4], l_i[4];
  floatx4 acc[2][4];
#pragma unroll
  for (int i = 0; i < 4; ++i) { m_i[i] = -3.0e38f; l_i[i] = 0.0f; }
#pragma unroll
  for (int mb = 0; mb < 2; ++mb)
#pragma unroll
    for (int nb = 0; nb < 4; ++nb)
#pragma unroll
      for (int r = 0; r < 4; ++r) acc[mb][nb][r] = 0.0f;

  int kstart, iters;
  if (PARTIAL) {
    const int slice = blockIdx.z * 4 + w;          // 0..11
    iters  = (slice < 8) ? 11 : 10;
    kstart = (slice < 8) ? slice * 352 : 2816 + (slice - 8) * 320;
  } else {
    iters  = 32;
    kstart = w * 1024;
  }
  const float4* K4 = (const float4*)Ksg;
  const float NEG_HALF_LOG2E = -0.72134752044448170f;  // -0.5*log2(e)

  const int krow = (lane >> 4);
  const int kci  = lane & 15;

  // V B-frag global base: lane (quad,l15) of frag nb reads
  // Vt[b][nb*16+l15][k=kstart+it*32+quad*8 .. +8] (16B, L2-resident).
  const unsigned short* vg0 = Vtg + ((size_t)b * 64 + l15) * NKK + kstart + quad * 8;

  float4 kpre[8];
  uint4 vtpre[4];
#pragma unroll
  for (int c = 0; c < 8; ++c)
    kpre[c] = K4[(size_t)(b * NKK + kstart + c * 4 + krow) * 16 + kci];
#pragma unroll
  for (int nb = 0; nb < 4; ++nb)
    vtpre[nb] = *(const uint4*)(vg0 + (size_t)nb * 16 * NKK);

  const floatx4* qb = (const floatx4*)&qsA[lq * FSTRIDE];
  const floatx4* kb = (const floatx4*)&ksA[w][lk * FSTRIDE];

  for (int it = 0; it < iters; ++it) {
    // ---- store prefetched K tile -> LDS (wave-private, no barrier) ----
#pragma unroll
    for (int c = 0; c < 8; ++c)
      *(float4*)&ksA[w][(c * 4 + krow) * FSTRIDE + kci * 4] = kpre[c];

    // ---- prefetch next K tile ----
    {
      const int itn = (it + 1 < iters) ? it + 1 : it;
#pragma unroll
      for (int c = 0; c < 8; ++c)
        kpre[c] = K4[(size_t)(b * NKK + kstart + itn * 32 + c * 4 + krow) * 16 + kci];
    }

    // ---- score: s[i][j] = sum_d |Ks[lk+8j] - Qs[lq+8i]|, 1.5 VALU/dim ----
    float s[4][4];
#pragma unroll
    for (int i = 0; i < 4; ++i)
#pragma unroll
      for (int j = 0; j < 4; ++j) s[i][j] = 0.0f;

#pragma unroll
    for (int dc = 0; dc < 16; ++dc) {
      floatx4 qv[4], kv[4];
#pragma unroll
      for (int i = 0; i < 4; ++i) qv[i] = qb[i * (8 * FSTRIDE4) + dc];
#pragma unroll
      for (int j = 0; j < 4; ++j) kv[j] = kb[j * (8 * FSTRIDE4) + dc];
#pragma unroll
      for (int i = 0; i < 4; ++i) {
        const floatx2 qlo = qv[i].lo, qhi = qv[i].hi;
#pragma unroll
        for (int j = 0; j < 4; ++j) {
          floatx2 d0 = pk_sub(qlo, kv[j].lo);
          floatx2 d1 = pk_sub(qhi, kv[j].hi);
          s[i][j] += __builtin_fabsf(d0.x);
          s[i][j] += __builtin_fabsf(d0.y);
          s[i][j] += __builtin_fabsf(d1.x);
          s[i][j] += __builtin_fabsf(d1.y);
        }
      }
    }

    // ---- online softmax (base-2); row max via min(s); l per-lane ----
    float a_row[4];
#pragma unroll
    for (int i = 0; i < 4; ++i) {
      float smin = fminf(fminf(s[i][0], s[i][1]), fminf(s[i][2], s[i][3]));
      smin = fminf(smin, __shfl_xor(smin, 1));
      smin = fminf(smin, __shfl_xor(smin, 2));
      smin = fminf(smin, __shfl_xor(smin, 4));
      const float tmax = smin * smin * NEG_HALF_LOG2E;
      const float mn = fmaxf(m_i[i], tmax);
      a_row[i] = fexp2(m_i[i] - mn);
      m_i[i] = mn;
      float ps = 0.0f;
#pragma unroll
      for (int j = 0; j < 4; ++j) {
        const float sv = s[i][j];
        const float e = fexp2(fmaf(sv * NEG_HALF_LOG2E, sv, -mn));
        ps += e;
        psB[w][(lq + 8 * i) * PSTRIDE + lk + 8 * j] = (unsigned short)(fbits(e) >> 16);
      }
      l_i[i] = fmaf(l_i[i], a_row[i], ps);
    }
    if (lk == 0) {
#pragma unroll
      for (int i = 0; i < 4; ++i) abA[w][lq + 8 * i] = a_row[i];
    }

    // ---- P.V on MFMA (B-frags straight from prefetched registers) ----
    {
      bf16x8 afrag[2];
#pragma unroll
      for (int mb = 0; mb < 2; ++mb)
        afrag[mb] = *(const bf16x8*)&psB[w][(mb * 16 + l15) * PSTRIDE + quad * 8];

      const floatx4 arv0 = *(const floatx4*)&abA[w][quad * 4];
      const floatx4 arv1 = *(const floatx4*)&abA[w][16 + quad * 4];

#pragma unroll
      for (int nb = 0; nb < 4; ++nb) {
        bf16x8 bfrag = __builtin_bit_cast(bf16x8, vtpre[nb]);
        acc[0][nb] *= arv0;
        acc[1][nb] *= arv1;
        acc[0][nb] = __builtin_amdgcn_mfma_f32_16x16x32_bf16(afrag[0], bfrag, acc[0][nb], 0, 0, 0);
        acc[1][nb] = __builtin_amdgcn_mfma_f32_16x16x32_bf16(afrag[1], bfrag, acc[1][nb], 0, 0, 0);
      }
    }

    // ---- prefetch next V tile (used next iter; full iter of latency slack) ----
    {
      const int itn = (it + 1 < iters) ? it + 1 : it;
#pragma unroll
      for (int nb = 0; nb < 4; ++nb)
        vtpre[nb] = *(const uint4*)(vg0 + (size_t)nb * 16 * NKK + itn * 32);
    }
  }

  // ---- epilogue: reduce l across lk; publish m,l (overlay on psB[w]) + O ----
#pragma unroll
  for (int i = 0; i < 4; ++i) {
    float l = l_i[i];
    l += __shfl_xor(l, 1);
    l += __shfl_xor(l, 2);
    l += __shfl_xor(l, 4);
    l_i[i] = l;
  }
  float* ovl = (float*)&psB[w][0];   // psB[w] dead after last P.V (wave-private)
  if (lk == 0) {
#pragma unroll
    for (int i = 0; i < 4; ++i) {
      ovl[lq + 8 * i]      = m_i[i];
      ovl[32 + lq + 8 * i] = l_i[i];
    }
  }
#pragma unroll
  for (int mb = 0; mb < 2; ++mb)
#pragma unroll
    for (int nb = 0; nb < 4; ++nb)
#pragma unroll
      for (int r = 0; r < 4; ++r)
        ksA[w][(mb * 16 + quad * 4 + r) * 64 + nb * 16 + l15] = acc[mb][nb][r];
  __syncthreads();

  {
    const int q = tid >> 3;
    const int dbase = (tid & 7) * 8;
    const float m0 = ((const float*)&psB[0][0])[q];
    const float m1 = ((const float*)&psB[1][0])[q];
    const float m2 = ((const float*)&psB[2][0])[q];
    const float m3 = ((const float*)&psB[3][0])[q];
    const float M = fmaxf(fmaxf(m0, m1), fmaxf(m2, m3));
    const float s0 = fexp2(m0 - M), s1 = fexp2(m1 - M);
    const float s2v = fexp2(m2 - M), s3 = fexp2(m3 - M);
    const float L = ((const float*)&psB[0][0])[32 + q] * s0 +
                    ((const float*)&psB[1][0])[32 + q] * s1 +
                    ((const float*)&psB[2][0])[32 + q] * s2v +
                    ((const float*)&psB[3][0])[32 + q] * s3;
    if (PARTIAL) {
      const size_t p = (size_t)(blockIdx.z * 4 + b) * 128 + blockIdx.x;
      if (dbase == 0) { Pm[p * 32 + q] = M; Pl[p * 32 + q] = L; }
      float* dst = PO + p * 2048 + q * 64 + dbase;
#pragma unroll
      for (int c = 0; c < 8; ++c) {
        const int d = dbase + c;
        dst[c] = s0 * ksA[0][q * 64 + d] + s1 * ksA[1][q * 64 + d] +
                 s2v * ksA[2][q * 64 + d] + s3 * ksA[3][q * 64 + d];
      }
    } else {
      const float rL = 1.0f / L;
      const size_t gbase = (size_t)(b * NQQ + qt + q) * 64 + dbase;
#pragma unroll
      for (int c = 0; c < 8; ++c) {
        const int d = dbase + c;
        float o = s0 * ksA[0][q * 64 + d] + s1 * ksA[1][q * 64 + d] +
                  s2v * ksA[2][q * 64 + d] + s3 * ksA[3][q * 64 + d];
        outp[gbase + c] = o * rL * Wog[gbase + c];
      }
    }
  }
}

// ---------------------------------------------------------------------------
// Merge the 3 key-split partials: out = sum_s(w_s O_s)/L * Wo.
// ---------------------------------------------------------------------------
__global__ __launch_bounds__(256) void amerge_kernel(
    const float* __restrict__ Pm, const float* __restrict__ Pl,
    const float* __restrict__ PO, const float* __restrict__ Wog,
    float* __restrict__ outp)
{
  const int tid = threadIdx.x;
  const int qt = blockIdx.x;
  const int b = blockIdx.y;
  const int q = tid >> 3;
  const int dbase = (tid & 7) * 8;
  size_t p[3];
  float mv[3], lv[3];
#pragma unroll
  for (int s = 0; s < 3; ++s) {
    p[s] = (size_t)(s * 4 + b) * 128 + qt;
    mv[s] = Pm[p[s] * 32 + q];
    lv[s] = Pl[p[s] * 32 + q];
  }
  const float M = fmaxf(fmaxf(mv[0], mv[1]), mv[2]);
  float wsum = 0.0f, wgt[3];
#pragma unroll
  for (int s = 0; s < 3; ++s) { wgt[s] = fexp2(mv[s] - M); wsum += wgt[s] * lv[s]; }
  const float rL = 1.0f / wsum;
  const size_t g = ((size_t)b * NQQ + qt * 32 + q) * 64 + dbase;
#pragma unroll
  for (int c = 0; c < 8; ++c) {
    float o = 0.0f;
#pragma unroll
    for (int s = 0; s < 3; ++s) o += wgt[s] * PO[p[s] * 2048 + q * 64 + dbase + c];
    outp[g + c] = o * rL * Wog[g + c];
  }
}

// ---------------------------------------------------------------------------
extern "C" void kernel_launch(void* const* d_in, const int* in_sizes, int n_in,
                              void* d_out, int out_size, void* d_ws, size_t ws_size,
                              hipStream_t stream) {
  (void)in_sizes; (void)n_in; (void)out_size;
  const float* KEY   = (const float*)d_in[0];
  const float* VALUE = (const float*)d_in[1];
  const float* QUERY = (const float*)d_in[2];
  const float* W1w = (const float*)d_in[3];
  const float* W1b = (const float*)d_in[4];
  const float* W2w = (const float*)d_in[5];
  const float* W2b = (const float*)d_in[6];
  const float* W3w = (const float*)d_in[7];
  const float* W3b = (const float*)d_in[8];
  const float* Wo1w = (const float*)d_in[9];
  const float* Wo1b = (const float*)d_in[10];
  const float* Wo2w = (const float*)d_in[11];
  const float* Wo2b = (const float*)d_in[12];
  const float* Wo3w = (const float*)d_in[13];
  const float* Wo3b = (const float*)d_in[14];

  float* ws = (float*)d_ws;
  const size_t tsz = (size_t)B_DIM * NKK * DD;  // 1,048,576 floats
  float* Ks = ws;
  float* Qs = ws + tsz;
  float* Wo = ws + 2 * tsz;
  unsigned short* Vtg = (unsigned short*)(ws + 3 * tsz);  // tsz ushorts (2 MB)
  unsigned short* sp  = Vtg + tsz;                        // 2x196608 ushorts
  float* Pm = ws + 3 * tsz + tsz / 2 + 196608;            // partial maxes (12x128x32)
  float* Pl = Pm + 49152;
  float* PO = Pl + 49152;                                 // 12x128x2048 floats
  float* outf = (float*)d_out;

  const size_t ws_need = (size_t)(3 * tsz + tsz / 2 + 196608 + 2 * 49152 + 3145728) * 4;
  const bool partial = ws_size >= ws_need;   // deterministic across calls

  wsplit_kernel<<<dim3(768), 256, 0, stream>>>(W1w, W2w, W3w, Wo1w, Wo2w, Wo3w, sp);
  vtrans_kernel<<<dim3(NKK / 64, B_DIM), 256, 0, stream>>>(VALUE, Vtg);
  mlpmm_kernel<<<dim3(768), 512, 0, stream>>>(
      KEY, QUERY, W1b, W2b, W3b, Wo1b, Wo2b, Wo3b, sp, Ks, Qs, Wo);
  if (partial) {
    attn_kernel<true><<<dim3(NQQ / 32, B_DIM, 3), 256, 0, stream>>>(
        Ks, Qs, Vtg, Wo, outf, Pm, Pl, PO);
    amerge_kernel<<<dim3(NQQ / 32, B_DIM), 256, 0, stream>>>(Pm, Pl, PO, Wo, outf);
  } else {
    attn_kernel<false><<<dim3(NQQ / 32, B_DIM, 1), 256, 0, stream>>>(
        Ks, Qs, Vtg, Wo, outf, Pm, Pl, PO);
  }
}